// Round 11
// baseline (276.569 us; speedup 1.0000x reference)
//
#include <hip/hip_runtime.h>

#define B_ 8
#define L_ 2048
#define E_ 256
#define H_ 4
#define D_ 64

typedef __bf16 bf16;
typedef __bf16 bf16x8 __attribute__((ext_vector_type(8)));
typedef __bf16 bf16x4 __attribute__((ext_vector_type(4)));
typedef float  f32x4  __attribute__((ext_vector_type(4)));
typedef float  f32x16 __attribute__((ext_vector_type(16)));

// Ŝ = (q·k)/8 * log2(e); softmax entirely in exp2 domain.
#define QSCALE 0.1803368801111244f

__device__ __forceinline__ float fexp2(float x) { return __builtin_amdgcn_exp2f(x); }
__device__ __forceinline__ float flog2(float x) { return __builtin_amdgcn_logf(x); }

// Barrier that drains LDS ops but NOT global loads (vmcnt stays in flight).
// Safe when all cross-wave communication is through LDS.
__device__ __forceinline__ void barrier_lds() {
    asm volatile("s_waitcnt lgkmcnt(0)" ::: "memory");
    __builtin_amdgcn_s_barrier();
}

// ---------------------------------------------------------------------------
// Kernel 0 (fused): blocks 0..4095 convert x -> bf16 xb [B,L,E];
// blocks 4096..4863 repack weights -> Wcat[768][256].
// ---------------------------------------------------------------------------
__global__ void prep_kernel(const float* __restrict__ x,
                            const float* __restrict__ in_proj_w,
                            const float* __restrict__ W_gnn,
                            bf16* __restrict__ xb, bf16* __restrict__ Wcat) {
    int bid = blockIdx.x;
    if (bid < 4096) {
        size_t i = ((size_t)bid * 256 + threadIdx.x) * 4;
        f32x4 v = *(const f32x4*)&x[i];
        bf16x4 o;
#pragma unroll
        for (int j = 0; j < 4; j++) o[j] = (bf16)v[j];
        *(bf16x4*)&xb[i] = o;
    } else {
        int r = bid - 4096;
        int e = threadIdx.x;
        float v = (r < 512) ? in_proj_w[r * E_ + e] : W_gnn[e * E_ + (r - 512)];
        Wcat[r * E_ + e] = (bf16)v;
    }
}

// ---------------------------------------------------------------------------
// Kernel 2: projections. C[M=16384, N=768] = x @ Wcat^T (bf16 MFMA, fp32 acc)
//   by==0 -> Qs ; by==1 -> Ks ; by==2 -> XWT[B,E,L]
// (256,2): r8 measured (256,4) costs ~10us (VGPR cap throttles staging).
// ---------------------------------------------------------------------------
__global__ __launch_bounds__(256, 2) void proj_kernel(
    const bf16* __restrict__ xb, const bf16* __restrict__ Wcat,
    const float* __restrict__ in_proj_b, const float* __restrict__ B_gnn,
    bf16* __restrict__ Qs, bf16* __restrict__ Ks, bf16* __restrict__ XWT) {
    int tid  = threadIdx.x;
    int lane = tid & 63, wave = tid >> 6;
    int l16  = lane & 15, quad = lane >> 4;
    int m0 = blockIdx.x * 64 + wave * 16;
    int by = blockIdx.y;
    int n0 = by * 256;

    f32x4 acc[16];
#pragma unroll
    for (int i = 0; i < 16; i++) acc[i] = (f32x4){0.f, 0.f, 0.f, 0.f};

    const bf16* xrow = xb + (size_t)(m0 + l16) * E_;
    for (int ks = 0; ks < 8; ks++) {
        int koff = ks * 32 + quad * 8;
        bf16x8 af = *(const bf16x8*)&xrow[koff];
#pragma unroll
        for (int nt = 0; nt < 16; nt++) {
            bf16x8 bfv = *(const bf16x8*)&Wcat[(size_t)(n0 + nt * 16 + l16) * E_ + koff];
            acc[nt] = __builtin_amdgcn_mfma_f32_16x16x32_bf16(af, bfv, acc[nt], 0, 0, 0);
        }
    }

#pragma unroll
    for (int nt = 0; nt < 16; nt++) {
        int n = n0 + nt * 16 + l16;
        if (by == 0) {
            float bias = in_proj_b[n];
#pragma unroll
            for (int r = 0; r < 4; r++) {
                int m = m0 + quad * 4 + r;
                Qs[(size_t)m * E_ + n] = (bf16)((acc[nt][r] + bias) * QSCALE);
            }
        } else if (by == 1) {
            float bias = in_proj_b[n];
            int col = n - 256;
#pragma unroll
            for (int r = 0; r < 4; r++) {
                int m = m0 + quad * 4 + r;
                Ks[(size_t)m * E_ + col] = (bf16)(acc[nt][r] + bias);
            }
        } else {
            int nc = n - 512;
            float bias = B_gnn[nc];
            int m = m0 + quad * 4;
            int b = m >> 11, l = m & 2047;
            bf16x4 pk;
#pragma unroll
            for (int r = 0; r < 4; r++) pk[r] = (bf16)(acc[nt][r] + bias);
            *(bf16x4*)&XWT[((size_t)b * E_ + nc) * L_ + l] = pk;
        }
    }
}

// ---------------------------------------------------------------------------
// Kernel 3: softmax stats (r7 structure + T5 setprio around MFMA cluster;
// 4 independent blocks/CU at drifting phases -> priority pays here).
// ---------------------------------------------------------------------------
__global__ __launch_bounds__(256, 4) void stats_kernel(
    const bf16* __restrict__ Qs, const bf16* __restrict__ Ks,
    float* __restrict__ o) {
    __shared__ bf16 ldsK[2][64 * 72];
    int tid  = threadIdx.x;
    int lane = tid & 63, wave = tid >> 6;
    int r32  = lane & 31, half = lane >> 5;
    int qt = blockIdx.x, h = blockIdx.y, b = blockIdx.z;
    int q0 = qt * 128 + wave * 32;

    bf16x8 qa[4];
    const bf16* qrow = Qs + ((size_t)b * L_ + q0 + r32) * E_ + h * D_;
#pragma unroll
    for (int c = 0; c < 4; c++) qa[c] = *(const bf16x8*)&qrow[c * 16 + half * 8];

    float lsum[16];
#pragma unroll
    for (int i = 0; i < 16; i++) lsum[i] = 0.f;

    const bf16* Kb = Ks + (size_t)b * L_ * E_ + h * D_;

#pragma unroll
    for (int it = 0; it < 2; it++) {
        int idx = it * 256 + tid;
        int key = idx >> 3, dc = (idx & 7) * 8;
        *(bf16x8*)&ldsK[0][key * 72 + dc] =
            *(const bf16x8*)&Kb[(size_t)key * E_ + dc];
    }
    __syncthreads();

    int cur = 0;
    for (int kt = 0; kt < 32; kt++) {
        bf16x8 pk0, pk1;
        if (kt < 31) {
            int idx0 = tid, idx1 = 256 + tid;
            pk0 = *(const bf16x8*)&Kb[(size_t)((kt + 1) * 64 + (idx0 >> 3)) * E_ + (idx0 & 7) * 8];
            pk1 = *(const bf16x8*)&Kb[(size_t)((kt + 1) * 64 + (idx1 >> 3)) * E_ + (idx1 & 7) * 8];
        }
#pragma unroll
        for (int nt = 0; nt < 2; nt++) {
            f32x16 S = {};
            __builtin_amdgcn_s_setprio(1);
#pragma unroll
            for (int c = 0; c < 4; c++) {
                bf16x8 kb = *(const bf16x8*)&ldsK[cur][(nt * 32 + r32) * 72 + c * 16 + half * 8];
                S = __builtin_amdgcn_mfma_f32_32x32x16_bf16(qa[c], kb, S, 0, 0, 0);
            }
            __builtin_amdgcn_s_setprio(0);
#pragma unroll
            for (int i = 0; i < 16; i++) lsum[i] += fexp2(S[i]);
        }
        if (kt < 31) {
            int idx0 = tid, idx1 = 256 + tid;
            *(bf16x8*)&ldsK[cur ^ 1][(idx0 >> 3) * 72 + (idx0 & 7) * 8] = pk0;
            *(bf16x8*)&ldsK[cur ^ 1][(idx1 >> 3) * 72 + (idx1 & 7) * 8] = pk1;
        }
        barrier_lds();
        cur ^= 1;
    }
#pragma unroll
    for (int i = 0; i < 16; i++) {
        float v = lsum[i];
        v += __shfl_xor(v, 1); v += __shfl_xor(v, 2); v += __shfl_xor(v, 4);
        v += __shfl_xor(v, 8); v += __shfl_xor(v, 16);
        lsum[i] = v;
    }
    if (r32 == 0) {
        float* op = o + ((size_t)(b * H_ + h)) * L_ + q0;
#pragma unroll
        for (int i = 0; i < 16; i++) {
            int row = (i & 3) + 8 * (i >> 2) + 4 * half;
            op[row] = -(2.0f + flog2(lsum[i]));
        }
    }
}

// ---------------------------------------------------------------------------
// Kernel 4: pass 2 (r6 proven structure, 66 us x3 reproduced: T14 prefetch,
// 3 lgkm-only barriers/iter, prefetch LDS-writes after barrier A) + T5
// setprio around the MFMA clusters (2 independent blocks/CU drift out of
// phase -> MFMA-phase wave wins issue slots).
// r10 lesson: any variant with >~190 live regs gets spilled (WRITE_SIZE
// tripwire). This structure is 128 VGPR, no spill.
// ---------------------------------------------------------------------------
__global__ __launch_bounds__(256, 2) void pass2_kernel(
    const bf16* __restrict__ Qs, const bf16* __restrict__ Ks,
    const bf16* __restrict__ XWT, const float* __restrict__ o,
    float* __restrict__ Opart) {
    __shared__ alignas(16) unsigned char smem[79872];
    bf16* ldsK  = (bf16*)smem;             // [64 keys][264 = 256 E + 8 pad]
    bf16* ldsXW = (bf16*)(smem + 33792);   // [256 n][72 = 64 k + 8 pad]
    bf16* ldsP  = (bf16*)(smem + 70656);   // [64 q][72 = 64 k + 8 pad]

    int tid  = threadIdx.x;
    int lane = tid & 63, wave = tid >> 6;
    int l32  = lane & 31, half = lane >> 5;
    int qh = wave & 1, kh = wave >> 1;   // QK role: q-half, k-half
    int nh = kh;                          // PV role: n-half (128 cols)

    int flat = blockIdx.x;
    int b   = flat & 7;
    int qt  = (flat >> 3) & 31;
    int ksp = flat >> 8;

    int qw = qt * 64 + qh * 32 + l32;    // this lane's q row in QK phase

    // Q B-frags for all 4 heads (B-layout: n=lane&31=q, k=(lane>>5)*8+j)
    bf16x8 qf[4][4];
    const bf16* qrow = Qs + ((size_t)b * L_ + qw) * E_;
#pragma unroll
    for (int h = 0; h < H_; h++)
#pragma unroll
        for (int c = 0; c < 4; c++)
            qf[h][c] = *(const bf16x8*)&qrow[h * 64 + c * 16 + half * 8];

    float oh[4];
#pragma unroll
    for (int h = 0; h < H_; h++)
        oh[h] = o[((size_t)(b * H_ + h)) * L_ + qw];

    f32x16 zero = {};
    f32x16 acc[4];
#pragma unroll
    for (int i = 0; i < 4; i++) acc[i] = zero;

    const bf16* Kb = Ks + (size_t)b * L_ * E_;
    const bf16* Xb = XWT + (size_t)b * E_ * L_;

    // prologue: stage tile 0 directly to LDS
    {
        int k0 = ksp * 1024;
#pragma unroll
        for (int it = 0; it < 8; it++) {
            int idx = it * 256 + tid;
            int key = idx >> 5, col = (idx & 31) * 8;
            *(bf16x8*)&ldsK[key * 264 + col] =
                *(const bf16x8*)&Kb[(size_t)(k0 + key) * E_ + col];
        }
#pragma unroll
        for (int it = 0; it < 8; it++) {
            int idx = it * 256 + tid;
            int n = idx >> 3, kc = (idx & 7) * 8;
            *(bf16x8*)&ldsXW[n * 72 + kc] =
                *(const bf16x8*)&Xb[(size_t)n * L_ + k0 + kc];
        }
    }
    __syncthreads();

    for (int kt = 0; kt < 16; kt++) {
        // issue next tile's loads into registers (no wait; stays in flight
        // across the lgkm-only barriers below)
        bf16x8 pkf[8], pxf[8];
        if (kt < 15) {
            int k1 = ksp * 1024 + (kt + 1) * 64;
#pragma unroll
            for (int it = 0; it < 8; it++) {
                int idx = it * 256 + tid;
                int key = idx >> 5, col = (idx & 31) * 8;
                pkf[it] = *(const bf16x8*)&Kb[(size_t)(k1 + key) * E_ + col];
            }
#pragma unroll
            for (int it = 0; it < 8; it++) {
                int idx = it * 256 + tid;
                int n = idx >> 3, kc = (idx & 7) * 8;
                pxf[it] = *(const bf16x8*)&Xb[(size_t)n * L_ + k1 + kc];
            }
        }

        // QK: S^T quadrant (32 keys x 32 q) per head; P = sum_h exp2(S^T+o_h)
        f32x16 P = zero;
#pragma unroll
        for (int h = 0; h < H_; h++) {
            f32x16 s = zero;
            __builtin_amdgcn_s_setprio(1);
#pragma unroll
            for (int c = 0; c < 4; c++) {
                bf16x8 ka = *(const bf16x8*)&ldsK[(kh * 32 + l32) * 264 + h * 64 + c * 16 + half * 8];
                s = __builtin_amdgcn_mfma_f32_32x32x16_bf16(ka, qf[h][c], s, 0, 0, 0);
            }
            __builtin_amdgcn_s_setprio(0);
#pragma unroll
            for (int r = 0; r < 16; r++) P[r] += fexp2(s[r] + oh[h]);
        }

        // write P quadrant at TRUE key indices: regs 4g..4g+3 -> keys 8g+4*half+0..3
#pragma unroll
        for (int g = 0; g < 4; g++) {
            bf16x4 pk;
#pragma unroll
            for (int j = 0; j < 4; j++) pk[j] = (bf16)P[4 * g + j];
            *(bf16x4*)&ldsP[(qh * 32 + l32) * 72 + kh * 32 + g * 8 + half * 4] = pk;
        }
        barrier_lds();   // C: P published; QK reads of ldsK drained

        // PV: O[32q x 128n] += P[32q x 64k] @ XW[64k x 128n], n-half = nh
        __builtin_amdgcn_s_setprio(1);
#pragma unroll
        for (int kc = 0; kc < 4; kc++) {
            bf16x8 pa = *(const bf16x8*)&ldsP[(qh * 32 + l32) * 72 + kc * 16 + half * 8];
#pragma unroll
            for (int nt = 0; nt < 4; nt++) {
                bf16x8 xw = *(const bf16x8*)&ldsXW[(nh * 128 + nt * 32 + l32) * 72 + kc * 16 + half * 8];
                acc[nt] = __builtin_amdgcn_mfma_f32_32x32x16_bf16(pa, xw, acc[nt], 0, 0, 0);
            }
        }
        __builtin_amdgcn_s_setprio(0);
        barrier_lds();   // A: PV reads drained; ldsK/ldsXW free for rewrite

        if (kt < 15) {
            // write prefetched tile to LDS (compiler inserts the vmcnt wait
            // for the register dependency here -- the only vmcnt wait)
#pragma unroll
            for (int it = 0; it < 8; it++) {
                int idx = it * 256 + tid;
                int key = idx >> 5, col = (idx & 31) * 8;
                *(bf16x8*)&ldsK[key * 264 + col] = pkf[it];
            }
#pragma unroll
            for (int it = 0; it < 8; it++) {
                int idx = it * 256 + tid;
                int n = idx >> 3, kc = (idx & 7) * 8;
                *(bf16x8*)&ldsXW[n * 72 + kc] = pxf[it];
            }
            barrier_lds();   // B: next tile published
        }
    }

    // direct quadrant store (each wave owns disjoint 32q x 128n)
    float* Ob = Opart + ((size_t)ksp * B_ + b) * (size_t)L_ * E_
              + (size_t)(qt * 64 + qh * 32) * E_ + nh * 128;
#pragma unroll
    for (int nt = 0; nt < 4; nt++)
#pragma unroll
        for (int r = 0; r < 16; r++) {
            int row = (r & 3) + 8 * (r >> 2) + 4 * half;
            Ob[(size_t)row * E_ + nt * 32 + l32] = acc[nt][r];
        }
}

// ---------------------------------------------------------------------------
// Kernel 5: sum the 2 k-half partials -> fp32 out[B,L,E]
// ---------------------------------------------------------------------------
__global__ void reduce_kernel(const float* __restrict__ Op, float* __restrict__ out) {
    size_t i = ((size_t)blockIdx.x * 256 + threadIdx.x) * 4;
    const size_t BLE = (size_t)B_ * L_ * E_;
    f32x4 a = *(const f32x4*)&Op[i];
    f32x4 c = *(const f32x4*)&Op[BLE + i];
#pragma unroll
    for (int j = 0; j < 4; j++) a[j] += c[j];
    *(f32x4*)&out[i] = a;
}

// ---------------------------------------------------------------------------
extern "C" void kernel_launch(void* const* d_in, const int* in_sizes, int n_in,
                              void* d_out, int out_size, void* d_ws, size_t ws_size,
                              hipStream_t stream) {
    const float* x   = (const float*)d_in[0];
    const float* ipw = (const float*)d_in[1];
    const float* ipb = (const float*)d_in[2];
    const float* wg  = (const float*)d_in[3];
    const float* bg  = (const float*)d_in[4];

    char* ws = (char*)d_ws;
    bf16*  Qs    = (bf16*)(ws);
    bf16*  Ks    = (bf16*)(ws + 8388608);
    bf16*  XWT   = (bf16*)(ws + 16777216);
    float* o     = (float*)(ws + 25165824);
    float* Opart = (float*)(ws + 25427968);
    bf16*  xb    = (bf16*)(ws + 25427968);
    bf16*  Wcat  = (bf16*)(ws + 33816576);

    prep_kernel<<<4864, 256, 0, stream>>>(x, ipw, wg, xb, Wcat);
    proj_kernel<<<dim3(256, 3), 256, 0, stream>>>(xb, Wcat, ipb, bg, Qs, Ks, XWT);
    stats_kernel<<<dim3(16, 4, 8), 256, 0, stream>>>(Qs, Ks, o);
    pass2_kernel<<<512, 256, 0, stream>>>(Qs, Ks, XWT, o, Opart);
    reduce_kernel<<<4096, 256, 0, stream>>>(Opart, (float*)d_out);
}

// Round 12
// 219.499 us; speedup vs baseline: 1.2600x; 1.2600x over previous
//
#include <hip/hip_runtime.h>

#define B_ 8
#define L_ 2048
#define E_ 256
#define H_ 4
#define D_ 64

typedef __bf16 bf16;
typedef __bf16 bf16x8 __attribute__((ext_vector_type(8)));
typedef __bf16 bf16x4 __attribute__((ext_vector_type(4)));
typedef float  f32x4  __attribute__((ext_vector_type(4)));
typedef float  f32x16 __attribute__((ext_vector_type(16)));

// Ŝ = (q·k)/8 * log2(e); softmax entirely in exp2 domain.
#define QSCALE 0.1803368801111244f

__device__ __forceinline__ float fexp2(float x) { return __builtin_amdgcn_exp2f(x); }
__device__ __forceinline__ float flog2(float x) { return __builtin_amdgcn_logf(x); }

// Barrier that drains LDS ops but NOT global loads (vmcnt stays in flight).
// Safe when all cross-wave communication is through LDS.
__device__ __forceinline__ void barrier_lds() {
    asm volatile("s_waitcnt lgkmcnt(0)" ::: "memory");
    __builtin_amdgcn_s_barrier();
}

// ---------------------------------------------------------------------------
// Kernel 0 (fused): blocks 0..4095 convert x -> bf16 xb [B,L,E];
// blocks 4096..4863 repack weights -> Wcat[768][256].
// ---------------------------------------------------------------------------
__global__ void prep_kernel(const float* __restrict__ x,
                            const float* __restrict__ in_proj_w,
                            const float* __restrict__ W_gnn,
                            bf16* __restrict__ xb, bf16* __restrict__ Wcat) {
    int bid = blockIdx.x;
    if (bid < 4096) {
        size_t i = ((size_t)bid * 256 + threadIdx.x) * 4;
        f32x4 v = *(const f32x4*)&x[i];
        bf16x4 o;
#pragma unroll
        for (int j = 0; j < 4; j++) o[j] = (bf16)v[j];
        *(bf16x4*)&xb[i] = o;
    } else {
        int r = bid - 4096;
        int e = threadIdx.x;
        float v = (r < 512) ? in_proj_w[r * E_ + e] : W_gnn[e * E_ + (r - 512)];
        Wcat[r * E_ + e] = (bf16)v;
    }
}

// ---------------------------------------------------------------------------
// Kernel 2: projections. C[M=16384, N=768] = x @ Wcat^T (bf16 MFMA, fp32 acc)
//   by==0 -> Qs ; by==1 -> Ks ; by==2 -> XWT[B,E,L]
// (256,2): r8 measured (256,4) costs ~10us (VGPR cap throttles staging).
// ---------------------------------------------------------------------------
__global__ __launch_bounds__(256, 2) void proj_kernel(
    const bf16* __restrict__ xb, const bf16* __restrict__ Wcat,
    const float* __restrict__ in_proj_b, const float* __restrict__ B_gnn,
    bf16* __restrict__ Qs, bf16* __restrict__ Ks, bf16* __restrict__ XWT) {
    int tid  = threadIdx.x;
    int lane = tid & 63, wave = tid >> 6;
    int l16  = lane & 15, quad = lane >> 4;
    int m0 = blockIdx.x * 64 + wave * 16;
    int by = blockIdx.y;
    int n0 = by * 256;

    f32x4 acc[16];
#pragma unroll
    for (int i = 0; i < 16; i++) acc[i] = (f32x4){0.f, 0.f, 0.f, 0.f};

    const bf16* xrow = xb + (size_t)(m0 + l16) * E_;
    for (int ks = 0; ks < 8; ks++) {
        int koff = ks * 32 + quad * 8;
        bf16x8 af = *(const bf16x8*)&xrow[koff];
#pragma unroll
        for (int nt = 0; nt < 16; nt++) {
            bf16x8 bfv = *(const bf16x8*)&Wcat[(size_t)(n0 + nt * 16 + l16) * E_ + koff];
            acc[nt] = __builtin_amdgcn_mfma_f32_16x16x32_bf16(af, bfv, acc[nt], 0, 0, 0);
        }
    }

#pragma unroll
    for (int nt = 0; nt < 16; nt++) {
        int n = n0 + nt * 16 + l16;
        if (by == 0) {
            float bias = in_proj_b[n];
#pragma unroll
            for (int r = 0; r < 4; r++) {
                int m = m0 + quad * 4 + r;
                Qs[(size_t)m * E_ + n] = (bf16)((acc[nt][r] + bias) * QSCALE);
            }
        } else if (by == 1) {
            float bias = in_proj_b[n];
            int col = n - 256;
#pragma unroll
            for (int r = 0; r < 4; r++) {
                int m = m0 + quad * 4 + r;
                Ks[(size_t)m * E_ + col] = (bf16)(acc[nt][r] + bias);
            }
        } else {
            int nc = n - 512;
            float bias = B_gnn[nc];
            int m = m0 + quad * 4;
            int b = m >> 11, l = m & 2047;
            bf16x4 pk;
#pragma unroll
            for (int r = 0; r < 4; r++) pk[r] = (bf16)(acc[nt][r] + bias);
            *(bf16x4*)&XWT[((size_t)b * E_ + nc) * L_ + l] = pk;
        }
    }
}

// ---------------------------------------------------------------------------
// Kernel 3: softmax stats (r7 version: dbuf ldsK, 1 lgkm barrier/iter).
// No setprio: r11 measured it perturbs codegen -> spill (FETCH 7x).
// ---------------------------------------------------------------------------
__global__ __launch_bounds__(256, 4) void stats_kernel(
    const bf16* __restrict__ Qs, const bf16* __restrict__ Ks,
    float* __restrict__ o) {
    __shared__ bf16 ldsK[2][64 * 72];
    int tid  = threadIdx.x;
    int lane = tid & 63, wave = tid >> 6;
    int r32  = lane & 31, half = lane >> 5;
    int qt = blockIdx.x, h = blockIdx.y, b = blockIdx.z;
    int q0 = qt * 128 + wave * 32;

    bf16x8 qa[4];
    const bf16* qrow = Qs + ((size_t)b * L_ + q0 + r32) * E_ + h * D_;
#pragma unroll
    for (int c = 0; c < 4; c++) qa[c] = *(const bf16x8*)&qrow[c * 16 + half * 8];

    float lsum[16];
#pragma unroll
    for (int i = 0; i < 16; i++) lsum[i] = 0.f;

    const bf16* Kb = Ks + (size_t)b * L_ * E_ + h * D_;

#pragma unroll
    for (int it = 0; it < 2; it++) {
        int idx = it * 256 + tid;
        int key = idx >> 3, dc = (idx & 7) * 8;
        *(bf16x8*)&ldsK[0][key * 72 + dc] =
            *(const bf16x8*)&Kb[(size_t)key * E_ + dc];
    }
    __syncthreads();

    int cur = 0;
    for (int kt = 0; kt < 32; kt++) {
        bf16x8 pk0, pk1;
        if (kt < 31) {
            int idx0 = tid, idx1 = 256 + tid;
            pk0 = *(const bf16x8*)&Kb[(size_t)((kt + 1) * 64 + (idx0 >> 3)) * E_ + (idx0 & 7) * 8];
            pk1 = *(const bf16x8*)&Kb[(size_t)((kt + 1) * 64 + (idx1 >> 3)) * E_ + (idx1 & 7) * 8];
        }
#pragma unroll
        for (int nt = 0; nt < 2; nt++) {
            f32x16 S = {};
#pragma unroll
            for (int c = 0; c < 4; c++) {
                bf16x8 kb = *(const bf16x8*)&ldsK[cur][(nt * 32 + r32) * 72 + c * 16 + half * 8];
                S = __builtin_amdgcn_mfma_f32_32x32x16_bf16(qa[c], kb, S, 0, 0, 0);
            }
#pragma unroll
            for (int i = 0; i < 16; i++) lsum[i] += fexp2(S[i]);
        }
        if (kt < 31) {
            int idx0 = tid, idx1 = 256 + tid;
            *(bf16x8*)&ldsK[cur ^ 1][(idx0 >> 3) * 72 + (idx0 & 7) * 8] = pk0;
            *(bf16x8*)&ldsK[cur ^ 1][(idx1 >> 3) * 72 + (idx1 & 7) * 8] = pk1;
        }
        barrier_lds();
        cur ^= 1;
    }
#pragma unroll
    for (int i = 0; i < 16; i++) {
        float v = lsum[i];
        v += __shfl_xor(v, 1); v += __shfl_xor(v, 2); v += __shfl_xor(v, 4);
        v += __shfl_xor(v, 8); v += __shfl_xor(v, 16);
        lsum[i] = v;
    }
    if (r32 == 0) {
        float* op = o + ((size_t)(b * H_ + h)) * L_ + q0;
#pragma unroll
        for (int i = 0; i < 16; i++) {
            int row = (i & 3) + 8 * (i >> 2) + 4 * half;
            op[row] = -(2.0f + flog2(lsum[i]));
        }
    }
}

// ---------------------------------------------------------------------------
// Kernel 4: pass 2 (r6 proven structure, 66 us x3 reproduced: T14 prefetch,
// 3 lgkm-only barriers/iter, prefetch LDS-writes after barrier A so the only
// vmcnt wait lands a full iteration after issue). No setprio (r11: spill).
// r1/r10/r11 lesson: variants whose live state exceeds ~190 regs (or whose
// scheduling is fenced) get silently spilled -- WRITE_SIZE > 37 MB is the
// tripwire. This structure: 128 VGPR, WRITE 36.9 MB, FETCH 14.5 MB.
// ---------------------------------------------------------------------------
__global__ __launch_bounds__(256, 2) void pass2_kernel(
    const bf16* __restrict__ Qs, const bf16* __restrict__ Ks,
    const bf16* __restrict__ XWT, const float* __restrict__ o,
    float* __restrict__ Opart) {
    __shared__ alignas(16) unsigned char smem[79872];
    bf16* ldsK  = (bf16*)smem;             // [64 keys][264 = 256 E + 8 pad]
    bf16* ldsXW = (bf16*)(smem + 33792);   // [256 n][72 = 64 k + 8 pad]
    bf16* ldsP  = (bf16*)(smem + 70656);   // [64 q][72 = 64 k + 8 pad]

    int tid  = threadIdx.x;
    int lane = tid & 63, wave = tid >> 6;
    int l32  = lane & 31, half = lane >> 5;
    int qh = wave & 1, kh = wave >> 1;   // QK role: q-half, k-half
    int nh = kh;                          // PV role: n-half (128 cols)

    int flat = blockIdx.x;
    int b   = flat & 7;
    int qt  = (flat >> 3) & 31;
    int ksp = flat >> 8;

    int qw = qt * 64 + qh * 32 + l32;    // this lane's q row in QK phase

    // Q B-frags for all 4 heads (B-layout: n=lane&31=q, k=(lane>>5)*8+j)
    bf16x8 qf[4][4];
    const bf16* qrow = Qs + ((size_t)b * L_ + qw) * E_;
#pragma unroll
    for (int h = 0; h < H_; h++)
#pragma unroll
        for (int c = 0; c < 4; c++)
            qf[h][c] = *(const bf16x8*)&qrow[h * 64 + c * 16 + half * 8];

    float oh[4];
#pragma unroll
    for (int h = 0; h < H_; h++)
        oh[h] = o[((size_t)(b * H_ + h)) * L_ + qw];

    f32x16 zero = {};
    f32x16 acc[4];
#pragma unroll
    for (int i = 0; i < 4; i++) acc[i] = zero;

    const bf16* Kb = Ks + (size_t)b * L_ * E_;
    const bf16* Xb = XWT + (size_t)b * E_ * L_;

    // prologue: stage tile 0 directly to LDS
    {
        int k0 = ksp * 1024;
#pragma unroll
        for (int it = 0; it < 8; it++) {
            int idx = it * 256 + tid;
            int key = idx >> 5, col = (idx & 31) * 8;
            *(bf16x8*)&ldsK[key * 264 + col] =
                *(const bf16x8*)&Kb[(size_t)(k0 + key) * E_ + col];
        }
#pragma unroll
        for (int it = 0; it < 8; it++) {
            int idx = it * 256 + tid;
            int n = idx >> 3, kc = (idx & 7) * 8;
            *(bf16x8*)&ldsXW[n * 72 + kc] =
                *(const bf16x8*)&Xb[(size_t)n * L_ + k0 + kc];
        }
    }
    __syncthreads();

    for (int kt = 0; kt < 16; kt++) {
        // issue next tile's loads into registers (no wait; stays in flight
        // across the lgkm-only barriers below)
        bf16x8 pkf[8], pxf[8];
        if (kt < 15) {
            int k1 = ksp * 1024 + (kt + 1) * 64;
#pragma unroll
            for (int it = 0; it < 8; it++) {
                int idx = it * 256 + tid;
                int key = idx >> 5, col = (idx & 31) * 8;
                pkf[it] = *(const bf16x8*)&Kb[(size_t)(k1 + key) * E_ + col];
            }
#pragma unroll
            for (int it = 0; it < 8; it++) {
                int idx = it * 256 + tid;
                int n = idx >> 3, kc = (idx & 7) * 8;
                pxf[it] = *(const bf16x8*)&Xb[(size_t)n * L_ + k1 + kc];
            }
        }

        // QK: S^T quadrant (32 keys x 32 q) per head; P = sum_h exp2(S^T+o_h)
        f32x16 P = zero;
#pragma unroll
        for (int h = 0; h < H_; h++) {
            f32x16 s = zero;
#pragma unroll
            for (int c = 0; c < 4; c++) {
                bf16x8 ka = *(const bf16x8*)&ldsK[(kh * 32 + l32) * 264 + h * 64 + c * 16 + half * 8];
                s = __builtin_amdgcn_mfma_f32_32x32x16_bf16(ka, qf[h][c], s, 0, 0, 0);
            }
#pragma unroll
            for (int r = 0; r < 16; r++) P[r] += fexp2(s[r] + oh[h]);
        }

        // write P quadrant at TRUE key indices: regs 4g..4g+3 -> keys 8g+4*half+0..3
#pragma unroll
        for (int g = 0; g < 4; g++) {
            bf16x4 pk;
#pragma unroll
            for (int j = 0; j < 4; j++) pk[j] = (bf16)P[4 * g + j];
            *(bf16x4*)&ldsP[(qh * 32 + l32) * 72 + kh * 32 + g * 8 + half * 4] = pk;
        }
        barrier_lds();   // C: P published; QK reads of ldsK drained

        // PV: O[32q x 128n] += P[32q x 64k] @ XW[64k x 128n], n-half = nh
#pragma unroll
        for (int kc = 0; kc < 4; kc++) {
            bf16x8 pa = *(const bf16x8*)&ldsP[(qh * 32 + l32) * 72 + kc * 16 + half * 8];
#pragma unroll
            for (int nt = 0; nt < 4; nt++) {
                bf16x8 xw = *(const bf16x8*)&ldsXW[(nh * 128 + nt * 32 + l32) * 72 + kc * 16 + half * 8];
                acc[nt] = __builtin_amdgcn_mfma_f32_32x32x16_bf16(pa, xw, acc[nt], 0, 0, 0);
            }
        }
        barrier_lds();   // A: PV reads drained; ldsK/ldsXW free for rewrite

        if (kt < 15) {
            // write prefetched tile to LDS (compiler inserts the vmcnt wait
            // for the register dependency here -- the only vmcnt wait)
#pragma unroll
            for (int it = 0; it < 8; it++) {
                int idx = it * 256 + tid;
                int key = idx >> 5, col = (idx & 31) * 8;
                *(bf16x8*)&ldsK[key * 264 + col] = pkf[it];
            }
#pragma unroll
            for (int it = 0; it < 8; it++) {
                int idx = it * 256 + tid;
                int n = idx >> 3, kc = (idx & 7) * 8;
                *(bf16x8*)&ldsXW[n * 72 + kc] = pxf[it];
            }
            barrier_lds();   // B: next tile published
        }
    }

    // direct quadrant store (each wave owns disjoint 32q x 128n)
    float* Ob = Opart + ((size_t)ksp * B_ + b) * (size_t)L_ * E_
              + (size_t)(qt * 64 + qh * 32) * E_ + nh * 128;
#pragma unroll
    for (int nt = 0; nt < 4; nt++)
#pragma unroll
        for (int r = 0; r < 16; r++) {
            int row = (r & 3) + 8 * (r >> 2) + 4 * half;
            Ob[(size_t)row * E_ + nt * 32 + l32] = acc[nt][r];
        }
}

// ---------------------------------------------------------------------------
// Kernel 5: sum the 2 k-half partials -> fp32 out[B,L,E]
// ---------------------------------------------------------------------------
__global__ void reduce_kernel(const float* __restrict__ Op, float* __restrict__ out) {
    size_t i = ((size_t)blockIdx.x * 256 + threadIdx.x) * 4;
    const size_t BLE = (size_t)B_ * L_ * E_;
    f32x4 a = *(const f32x4*)&Op[i];
    f32x4 c = *(const f32x4*)&Op[BLE + i];
#pragma unroll
    for (int j = 0; j < 4; j++) a[j] += c[j];
    *(f32x4*)&out[i] = a;
}

// ---------------------------------------------------------------------------
extern "C" void kernel_launch(void* const* d_in, const int* in_sizes, int n_in,
                              void* d_out, int out_size, void* d_ws, size_t ws_size,
                              hipStream_t stream) {
    const float* x   = (const float*)d_in[0];
    const float* ipw = (const float*)d_in[1];
    const float* ipb = (const float*)d_in[2];
    const float* wg  = (const float*)d_in[3];
    const float* bg  = (const float*)d_in[4];

    char* ws = (char*)d_ws;
    bf16*  Qs    = (bf16*)(ws);
    bf16*  Ks    = (bf16*)(ws + 8388608);
    bf16*  XWT   = (bf16*)(ws + 16777216);
    float* o     = (float*)(ws + 25165824);
    float* Opart = (float*)(ws + 25427968);
    bf16*  xb    = (bf16*)(ws + 25427968);
    bf16*  Wcat  = (bf16*)(ws + 33816576);

    prep_kernel<<<4864, 256, 0, stream>>>(x, ipw, wg, xb, Wcat);
    proj_kernel<<<dim3(256, 3), 256, 0, stream>>>(xb, Wcat, ipb, bg, Qs, Ks, XWT);
    stats_kernel<<<dim3(16, 4, 8), 256, 0, stream>>>(Qs, Ks, o);
    pass2_kernel<<<512, 256, 0, stream>>>(Qs, Ks, XWT, o, Opart);
    reduce_kernel<<<4096, 256, 0, stream>>>(Opart, (float*)d_out);
}

// Round 13
// 184.787 us; speedup vs baseline: 1.4967x; 1.1878x over previous
//
#include <hip/hip_runtime.h>

#define B_ 8
#define L_ 2048
#define E_ 256
#define H_ 4
#define D_ 64

typedef __bf16 bf16;
typedef __bf16 bf16x8 __attribute__((ext_vector_type(8)));
typedef __bf16 bf16x4 __attribute__((ext_vector_type(4)));
typedef float  f32x4  __attribute__((ext_vector_type(4)));
typedef float  f32x16 __attribute__((ext_vector_type(16)));

// Ŝ = (q·k)/8 * log2(e); softmax entirely in exp2 domain.
#define QSCALE 0.1803368801111244f

__device__ __forceinline__ float fexp2(float x) { return __builtin_amdgcn_exp2f(x); }
__device__ __forceinline__ float flog2(float x) { return __builtin_amdgcn_logf(x); }

// Barrier that drains LDS ops but NOT global loads (vmcnt stays in flight).
// Safe when all cross-wave communication is through LDS.
__device__ __forceinline__ void barrier_lds() {
    asm volatile("s_waitcnt lgkmcnt(0)" ::: "memory");
    __builtin_amdgcn_s_barrier();
}

// ---------------------------------------------------------------------------
// Kernel 0 (fused): blocks 0..4095 convert x -> bf16 xb [B,L,E];
// blocks 4096..4863 repack weights -> Wcat[768][256].
// ---------------------------------------------------------------------------
__global__ void prep_kernel(const float* __restrict__ x,
                            const float* __restrict__ in_proj_w,
                            const float* __restrict__ W_gnn,
                            bf16* __restrict__ xb, bf16* __restrict__ Wcat) {
    int bid = blockIdx.x;
    if (bid < 4096) {
        size_t i = ((size_t)bid * 256 + threadIdx.x) * 4;
        f32x4 v = *(const f32x4*)&x[i];
        bf16x4 o;
#pragma unroll
        for (int j = 0; j < 4; j++) o[j] = (bf16)v[j];
        *(bf16x4*)&xb[i] = o;
    } else {
        int r = bid - 4096;
        int e = threadIdx.x;
        float v = (r < 512) ? in_proj_w[r * E_ + e] : W_gnn[e * E_ + (r - 512)];
        Wcat[r * E_ + e] = (bf16)v;
    }
}

// ---------------------------------------------------------------------------
// Kernel 2: projections. C[M=16384, N=768] = x @ Wcat^T (bf16 MFMA, fp32 acc)
//   by==0 -> Qs ; by==1 -> Ks ; by==2 -> XWT[B,E,L]
// v2: Wcat tile staged in double-buffered LDS (was: every wave streamed the
// full 128KB column-block from L2, 4x redundant, latency-serialized).
// ldsW[2][256 n][36] pitch-36 -> 16-lane frag reads hit 16 distinct banks
// (18*l mod 32 all-distinct), full wave64 = 2-way max (free per m136).
// x row hoisted to af[8] regs (no latency-exposed loads in MFMA chain).
// One lgkm-only barrier per ks; prefetch ks+1 to regs during compute.
// ---------------------------------------------------------------------------
__global__ __launch_bounds__(256, 2) void proj_kernel(
    const bf16* __restrict__ xb, const bf16* __restrict__ Wcat,
    const float* __restrict__ in_proj_b, const float* __restrict__ B_gnn,
    bf16* __restrict__ Qs, bf16* __restrict__ Ks, bf16* __restrict__ XWT) {
    __shared__ bf16 ldsW[2][256 * 36];
    int tid  = threadIdx.x;
    int lane = tid & 63, wave = tid >> 6;
    int l16  = lane & 15, quad = lane >> 4;
    int m0 = blockIdx.x * 64 + wave * 16;
    int by = blockIdx.y;
    int n0 = by * 256;

    f32x4 acc[16];
#pragma unroll
    for (int i = 0; i < 16; i++) acc[i] = (f32x4){0.f, 0.f, 0.f, 0.f};

    // whole x row for this lane in registers (512 B = 8 x bf16x8)
    bf16x8 af[8];
    const bf16* xrow = xb + (size_t)(m0 + l16) * E_;
#pragma unroll
    for (int ks = 0; ks < 8; ks++) af[ks] = *(const bf16x8*)&xrow[ks * 32 + quad * 8];

    const bf16* Wb = Wcat + (size_t)n0 * E_;   // [256 n][256 k]

    // prologue: stage ks=0 tile (256 n x 32 k)
#pragma unroll
    for (int it = 0; it < 4; it++) {
        int idx = it * 256 + tid;
        int n = idx >> 2, c8 = (idx & 3) * 8;
        *(bf16x8*)&ldsW[0][n * 36 + c8] = *(const bf16x8*)&Wb[(size_t)n * E_ + c8];
    }
    __syncthreads();

    int cur = 0;
    for (int ks = 0; ks < 8; ks++) {
        // prefetch ks+1 tile to regs (in flight across compute)
        bf16x8 pw[4];
        if (ks < 7) {
#pragma unroll
            for (int it = 0; it < 4; it++) {
                int idx = it * 256 + tid;
                int n = idx >> 2, c8 = (idx & 3) * 8;
                pw[it] = *(const bf16x8*)&Wb[(size_t)n * E_ + (ks + 1) * 32 + c8];
            }
        }
#pragma unroll
        for (int nt = 0; nt < 16; nt++) {
            bf16x8 bfv = *(const bf16x8*)&ldsW[cur][(nt * 16 + l16) * 36 + quad * 8];
            acc[nt] = __builtin_amdgcn_mfma_f32_16x16x32_bf16(af[ks], bfv, acc[nt], 0, 0, 0);
        }
        if (ks < 7) {
#pragma unroll
            for (int it = 0; it < 4; it++) {
                int idx = it * 256 + tid;
                int n = idx >> 2, c8 = (idx & 3) * 8;
                *(bf16x8*)&ldsW[cur ^ 1][n * 36 + c8] = pw[it];
            }
        }
        barrier_lds();
        cur ^= 1;
    }

#pragma unroll
    for (int nt = 0; nt < 16; nt++) {
        int n = n0 + nt * 16 + l16;
        if (by == 0) {
            float bias = in_proj_b[n];
#pragma unroll
            for (int r = 0; r < 4; r++) {
                int m = m0 + quad * 4 + r;
                Qs[(size_t)m * E_ + n] = (bf16)((acc[nt][r] + bias) * QSCALE);
            }
        } else if (by == 1) {
            float bias = in_proj_b[n];
            int col = n - 256;
#pragma unroll
            for (int r = 0; r < 4; r++) {
                int m = m0 + quad * 4 + r;
                Ks[(size_t)m * E_ + col] = (bf16)(acc[nt][r] + bias);
            }
        } else {
            int nc = n - 512;
            float bias = B_gnn[nc];
            int m = m0 + quad * 4;
            int b = m >> 11, l = m & 2047;
            bf16x4 pk;
#pragma unroll
            for (int r = 0; r < 4; r++) pk[r] = (bf16)(acc[nt][r] + bias);
            *(bf16x4*)&XWT[((size_t)b * E_ + nc) * L_ + l] = pk;
        }
    }
}

// ---------------------------------------------------------------------------
// Kernel 3: softmax stats. 128-key double-buffered tiles (was 64): barriers
// 32 -> 16, prefetch depth 2 -> 4 loads/thread. ldsK[2][128x72] = 36.9 KB,
// still 4 blocks/CU. Same dbuf + lgkm-only-barrier recipe as r7 (+11 us).
// ---------------------------------------------------------------------------
__global__ __launch_bounds__(256, 4) void stats_kernel(
    const bf16* __restrict__ Qs, const bf16* __restrict__ Ks,
    float* __restrict__ o) {
    __shared__ bf16 ldsK[2][128 * 72];
    int tid  = threadIdx.x;
    int lane = tid & 63, wave = tid >> 6;
    int r32  = lane & 31, half = lane >> 5;
    int qt = blockIdx.x, h = blockIdx.y, b = blockIdx.z;
    int q0 = qt * 128 + wave * 32;

    bf16x8 qa[4];
    const bf16* qrow = Qs + ((size_t)b * L_ + q0 + r32) * E_ + h * D_;
#pragma unroll
    for (int c = 0; c < 4; c++) qa[c] = *(const bf16x8*)&qrow[c * 16 + half * 8];

    float lsum[16];
#pragma unroll
    for (int i = 0; i < 16; i++) lsum[i] = 0.f;

    const bf16* Kb = Ks + (size_t)b * L_ * E_ + h * D_;

    // prologue: stage keys 0..127 into buf 0
#pragma unroll
    for (int it = 0; it < 4; it++) {
        int idx = it * 256 + tid;
        int key = idx >> 3, dc = (idx & 7) * 8;
        *(bf16x8*)&ldsK[0][key * 72 + dc] =
            *(const bf16x8*)&Kb[(size_t)key * E_ + dc];
    }
    __syncthreads();

    int cur = 0;
    for (int kt = 0; kt < 16; kt++) {
        // issue next tile's loads (in flight across the compute phase)
        bf16x8 pk[4];
        if (kt < 15) {
#pragma unroll
            for (int it = 0; it < 4; it++) {
                int idx = it * 256 + tid;
                pk[it] = *(const bf16x8*)&Kb[(size_t)((kt + 1) * 128 + (idx >> 3)) * E_ + (idx & 7) * 8];
            }
        }
        // compute 4 x 32-key sub-tiles from buf[cur]
#pragma unroll
        for (int nt = 0; nt < 4; nt++) {
            f32x16 S = {};
#pragma unroll
            for (int c = 0; c < 4; c++) {
                bf16x8 kb = *(const bf16x8*)&ldsK[cur][(nt * 32 + r32) * 72 + c * 16 + half * 8];
                S = __builtin_amdgcn_mfma_f32_32x32x16_bf16(qa[c], kb, S, 0, 0, 0);
            }
#pragma unroll
            for (int i = 0; i < 16; i++) lsum[i] += fexp2(S[i]);
        }
        // write prefetch to the other buffer
        if (kt < 15) {
#pragma unroll
            for (int it = 0; it < 4; it++) {
                int idx = it * 256 + tid;
                *(bf16x8*)&ldsK[cur ^ 1][(idx >> 3) * 72 + (idx & 7) * 8] = pk[it];
            }
        }
        barrier_lds();
        cur ^= 1;
    }
#pragma unroll
    for (int i = 0; i < 16; i++) {
        float v = lsum[i];
        v += __shfl_xor(v, 1); v += __shfl_xor(v, 2); v += __shfl_xor(v, 4);
        v += __shfl_xor(v, 8); v += __shfl_xor(v, 16);
        lsum[i] = v;
    }
    if (r32 == 0) {
        float* op = o + ((size_t)(b * H_ + h)) * L_ + q0;
#pragma unroll
        for (int i = 0; i < 16; i++) {
            int row = (i & 3) + 8 * (i >> 2) + 4 * half;
            op[row] = -(2.0f + flog2(lsum[i]));
        }
    }
}

// ---------------------------------------------------------------------------
// Kernel 4: pass 2 (FROZEN: r6 structure, 66-69 us x4 reproduced: T14
// prefetch, 3 lgkm-only barriers/iter, prefetch LDS-writes after barrier A).
// r1/r10/r11 lesson: >~190 live regs or scheduling fences -> silent spill;
// WRITE_SIZE > 37 MB is the tripwire. This: 128 VGPR, WRITE 36.9, FETCH 14.5.
// ---------------------------------------------------------------------------
__global__ __launch_bounds__(256, 2) void pass2_kernel(
    const bf16* __restrict__ Qs, const bf16* __restrict__ Ks,
    const bf16* __restrict__ XWT, const float* __restrict__ o,
    float* __restrict__ Opart) {
    __shared__ alignas(16) unsigned char smem[79872];
    bf16* ldsK  = (bf16*)smem;             // [64 keys][264 = 256 E + 8 pad]
    bf16* ldsXW = (bf16*)(smem + 33792);   // [256 n][72 = 64 k + 8 pad]
    bf16* ldsP  = (bf16*)(smem + 70656);   // [64 q][72 = 64 k + 8 pad]

    int tid  = threadIdx.x;
    int lane = tid & 63, wave = tid >> 6;
    int l32  = lane & 31, half = lane >> 5;
    int qh = wave & 1, kh = wave >> 1;   // QK role: q-half, k-half
    int nh = kh;                          // PV role: n-half (128 cols)

    int flat = blockIdx.x;
    int b   = flat & 7;
    int qt  = (flat >> 3) & 31;
    int ksp = flat >> 8;

    int qw = qt * 64 + qh * 32 + l32;    // this lane's q row in QK phase

    // Q B-frags for all 4 heads (B-layout: n=lane&31=q, k=(lane>>5)*8+j)
    bf16x8 qf[4][4];
    const bf16* qrow = Qs + ((size_t)b * L_ + qw) * E_;
#pragma unroll
    for (int h = 0; h < H_; h++)
#pragma unroll
        for (int c = 0; c < 4; c++)
            qf[h][c] = *(const bf16x8*)&qrow[h * 64 + c * 16 + half * 8];

    float oh[4];
#pragma unroll
    for (int h = 0; h < H_; h++)
        oh[h] = o[((size_t)(b * H_ + h)) * L_ + qw];

    f32x16 zero = {};
    f32x16 acc[4];
#pragma unroll
    for (int i = 0; i < 4; i++) acc[i] = zero;

    const bf16* Kb = Ks + (size_t)b * L_ * E_;
    const bf16* Xb = XWT + (size_t)b * E_ * L_;

    // prologue: stage tile 0 directly to LDS
    {
        int k0 = ksp * 1024;
#pragma unroll
        for (int it = 0; it < 8; it++) {
            int idx = it * 256 + tid;
            int key = idx >> 5, col = (idx & 31) * 8;
            *(bf16x8*)&ldsK[key * 264 + col] =
                *(const bf16x8*)&Kb[(size_t)(k0 + key) * E_ + col];
        }
#pragma unroll
        for (int it = 0; it < 8; it++) {
            int idx = it * 256 + tid;
            int n = idx >> 3, kc = (idx & 7) * 8;
            *(bf16x8*)&ldsXW[n * 72 + kc] =
                *(const bf16x8*)&Xb[(size_t)n * L_ + k0 + kc];
        }
    }
    __syncthreads();

    for (int kt = 0; kt < 16; kt++) {
        // issue next tile's loads into registers (no wait; stays in flight
        // across the lgkm-only barriers below)
        bf16x8 pkf[8], pxf[8];
        if (kt < 15) {
            int k1 = ksp * 1024 + (kt + 1) * 64;
#pragma unroll
            for (int it = 0; it < 8; it++) {
                int idx = it * 256 + tid;
                int key = idx >> 5, col = (idx & 31) * 8;
                pkf[it] = *(const bf16x8*)&Kb[(size_t)(k1 + key) * E_ + col];
            }
#pragma unroll
            for (int it = 0; it < 8; it++) {
                int idx = it * 256 + tid;
                int n = idx >> 3, kc = (idx & 7) * 8;
                pxf[it] = *(const bf16x8*)&Xb[(size_t)n * L_ + k1 + kc];
            }
        }

        // QK: S^T quadrant (32 keys x 32 q) per head; P = sum_h exp2(S^T+o_h)
        f32x16 P = zero;
#pragma unroll
        for (int h = 0; h < H_; h++) {
            f32x16 s = zero;
#pragma unroll
            for (int c = 0; c < 4; c++) {
                bf16x8 ka = *(const bf16x8*)&ldsK[(kh * 32 + l32) * 264 + h * 64 + c * 16 + half * 8];
                s = __builtin_amdgcn_mfma_f32_32x32x16_bf16(ka, qf[h][c], s, 0, 0, 0);
            }
#pragma unroll
            for (int r = 0; r < 16; r++) P[r] += fexp2(s[r] + oh[h]);
        }

        // write P quadrant at TRUE key indices: regs 4g..4g+3 -> keys 8g+4*half+0..3
#pragma unroll
        for (int g = 0; g < 4; g++) {
            bf16x4 pk;
#pragma unroll
            for (int j = 0; j < 4; j++) pk[j] = (bf16)P[4 * g + j];
            *(bf16x4*)&ldsP[(qh * 32 + l32) * 72 + kh * 32 + g * 8 + half * 4] = pk;
        }
        barrier_lds();   // C: P published; QK reads of ldsK drained

        // PV: O[32q x 128n] += P[32q x 64k] @ XW[64k x 128n], n-half = nh
#pragma unroll
        for (int kc = 0; kc < 4; kc++) {
            bf16x8 pa = *(const bf16x8*)&ldsP[(qh * 32 + l32) * 72 + kc * 16 + half * 8];
#pragma unroll
            for (int nt = 0; nt < 4; nt++) {
                bf16x8 xw = *(const bf16x8*)&ldsXW[(nh * 128 + nt * 32 + l32) * 72 + kc * 16 + half * 8];
                acc[nt] = __builtin_amdgcn_mfma_f32_32x32x16_bf16(pa, xw, acc[nt], 0, 0, 0);
            }
        }
        barrier_lds();   // A: PV reads drained; ldsK/ldsXW free for rewrite

        if (kt < 15) {
            // write prefetched tile to LDS (compiler inserts the vmcnt wait
            // for the register dependency here -- the only vmcnt wait)
#pragma unroll
            for (int it = 0; it < 8; it++) {
                int idx = it * 256 + tid;
                int key = idx >> 5, col = (idx & 31) * 8;
                *(bf16x8*)&ldsK[key * 264 + col] = pkf[it];
            }
#pragma unroll
            for (int it = 0; it < 8; it++) {
                int idx = it * 256 + tid;
                int n = idx >> 3, kc = (idx & 7) * 8;
                *(bf16x8*)&ldsXW[n * 72 + kc] = pxf[it];
            }
            barrier_lds();   // B: next tile published
        }
    }

    // direct quadrant store (each wave owns disjoint 32q x 128n)
    float* Ob = Opart + ((size_t)ksp * B_ + b) * (size_t)L_ * E_
              + (size_t)(qt * 64 + qh * 32) * E_ + nh * 128;
#pragma unroll
    for (int nt = 0; nt < 4; nt++)
#pragma unroll
        for (int r = 0; r < 16; r++) {
            int row = (r & 3) + 8 * (r >> 2) + 4 * half;
            Ob[(size_t)row * E_ + nt * 32 + l32] = acc[nt][r];
        }
}

// ---------------------------------------------------------------------------
// Kernel 5: sum the 2 k-half partials -> fp32 out[B,L,E]
// ---------------------------------------------------------------------------
__global__ void reduce_kernel(const float* __restrict__ Op, float* __restrict__ out) {
    size_t i = ((size_t)blockIdx.x * 256 + threadIdx.x) * 4;
    const size_t BLE = (size_t)B_ * L_ * E_;
    f32x4 a = *(const f32x4*)&Op[i];
    f32x4 c = *(const f32x4*)&Op[BLE + i];
#pragma unroll
    for (int j = 0; j < 4; j++) a[j] += c[j];
    *(f32x4*)&out[i] = a;
}

// ---------------------------------------------------------------------------
extern "C" void kernel_launch(void* const* d_in, const int* in_sizes, int n_in,
                              void* d_out, int out_size, void* d_ws, size_t ws_size,
                              hipStream_t stream) {
    const float* x   = (const float*)d_in[0];
    const float* ipw = (const float*)d_in[1];
    const float* ipb = (const float*)d_in[2];
    const float* wg  = (const float*)d_in[3];
    const float* bg  = (const float*)d_in[4];

    char* ws = (char*)d_ws;
    bf16*  Qs    = (bf16*)(ws);
    bf16*  Ks    = (bf16*)(ws + 8388608);
    bf16*  XWT   = (bf16*)(ws + 16777216);
    float* o     = (float*)(ws + 25165824);
    float* Opart = (float*)(ws + 25427968);
    bf16*  xb    = (bf16*)(ws + 25427968);
    bf16*  Wcat  = (bf16*)(ws + 33816576);

    prep_kernel<<<4864, 256, 0, stream>>>(x, ipw, wg, xb, Wcat);
    proj_kernel<<<dim3(256, 3), 256, 0, stream>>>(xb, Wcat, ipb, bg, Qs, Ks, XWT);
    stats_kernel<<<dim3(16, 4, 8), 256, 0, stream>>>(Qs, Ks, o);
    pass2_kernel<<<512, 256, 0, stream>>>(Qs, Ks, XWT, o, Opart);
    reduce_kernel<<<4096, 256, 0, stream>>>(Opart, (float*)d_out);
}

// Round 15
// 174.695 us; speedup vs baseline: 1.5832x; 1.0578x over previous
//
#include <hip/hip_runtime.h>

#define B_ 8
#define L_ 2048
#define E_ 256
#define H_ 4
#define D_ 64

typedef __bf16 bf16;
typedef __bf16 bf16x8 __attribute__((ext_vector_type(8)));
typedef __bf16 bf16x4 __attribute__((ext_vector_type(4)));
typedef float  f32x4  __attribute__((ext_vector_type(4)));
typedef float  f32x16 __attribute__((ext_vector_type(16)));

// Ŝ = (q·k)/8 * log2(e); softmax entirely in exp2 domain.
#define QSCALE 0.1803368801111244f

__device__ __forceinline__ float fexp2(float x) { return __builtin_amdgcn_exp2f(x); }
__device__ __forceinline__ float flog2(float x) { return __builtin_amdgcn_logf(x); }

// Barrier that drains LDS ops but NOT global loads (vmcnt stays in flight).
// Safe when all cross-wave communication is through LDS.
__device__ __forceinline__ void barrier_lds() {
    asm volatile("s_waitcnt lgkmcnt(0)" ::: "memory");
    __builtin_amdgcn_s_barrier();
}

// ---------------------------------------------------------------------------
// Kernel 0 (fused): blocks 0..4095 convert x -> bf16 xb [B,L,E];
// blocks 4096..4863 repack weights -> Wcat[768][256].
// ---------------------------------------------------------------------------
__global__ void prep_kernel(const float* __restrict__ x,
                            const float* __restrict__ in_proj_w,
                            const float* __restrict__ W_gnn,
                            bf16* __restrict__ xb, bf16* __restrict__ Wcat) {
    int bid = blockIdx.x;
    if (bid < 4096) {
        size_t i = ((size_t)bid * 256 + threadIdx.x) * 4;
        f32x4 v = *(const f32x4*)&x[i];
        bf16x4 o;
#pragma unroll
        for (int j = 0; j < 4; j++) o[j] = (bf16)v[j];
        *(bf16x4*)&xb[i] = o;
    } else {
        int r = bid - 4096;
        int e = threadIdx.x;
        float v = (r < 512) ? in_proj_w[r * E_ + e] : W_gnn[e * E_ + (r - 512)];
        Wcat[r * E_ + e] = (bf16)v;
    }
}

// ---------------------------------------------------------------------------
// Kernel 2: projections (r13 version: Wcat dbuf LDS staging, +~15us win).
// ---------------------------------------------------------------------------
__global__ __launch_bounds__(256, 2) void proj_kernel(
    const bf16* __restrict__ xb, const bf16* __restrict__ Wcat,
    const float* __restrict__ in_proj_b, const float* __restrict__ B_gnn,
    bf16* __restrict__ Qs, bf16* __restrict__ Ks, bf16* __restrict__ XWT) {
    __shared__ bf16 ldsW[2][256 * 36];
    int tid  = threadIdx.x;
    int lane = tid & 63, wave = tid >> 6;
    int l16  = lane & 15, quad = lane >> 4;
    int m0 = blockIdx.x * 64 + wave * 16;
    int by = blockIdx.y;
    int n0 = by * 256;

    f32x4 acc[16];
#pragma unroll
    for (int i = 0; i < 16; i++) acc[i] = (f32x4){0.f, 0.f, 0.f, 0.f};

    bf16x8 af[8];
    const bf16* xrow = xb + (size_t)(m0 + l16) * E_;
#pragma unroll
    for (int ks = 0; ks < 8; ks++) af[ks] = *(const bf16x8*)&xrow[ks * 32 + quad * 8];

    const bf16* Wb = Wcat + (size_t)n0 * E_;

#pragma unroll
    for (int it = 0; it < 4; it++) {
        int idx = it * 256 + tid;
        int n = idx >> 2, c8 = (idx & 3) * 8;
        *(bf16x8*)&ldsW[0][n * 36 + c8] = *(const bf16x8*)&Wb[(size_t)n * E_ + c8];
    }
    __syncthreads();

    int cur = 0;
    for (int ks = 0; ks < 8; ks++) {
        bf16x8 pw[4];
        if (ks < 7) {
#pragma unroll
            for (int it = 0; it < 4; it++) {
                int idx = it * 256 + tid;
                int n = idx >> 2, c8 = (idx & 3) * 8;
                pw[it] = *(const bf16x8*)&Wb[(size_t)n * E_ + (ks + 1) * 32 + c8];
            }
        }
#pragma unroll
        for (int nt = 0; nt < 16; nt++) {
            bf16x8 bfv = *(const bf16x8*)&ldsW[cur][(nt * 16 + l16) * 36 + quad * 8];
            acc[nt] = __builtin_amdgcn_mfma_f32_16x16x32_bf16(af[ks], bfv, acc[nt], 0, 0, 0);
        }
        if (ks < 7) {
#pragma unroll
            for (int it = 0; it < 4; it++) {
                int idx = it * 256 + tid;
                int n = idx >> 2, c8 = (idx & 3) * 8;
                *(bf16x8*)&ldsW[cur ^ 1][n * 36 + c8] = pw[it];
            }
        }
        barrier_lds();
        cur ^= 1;
    }

#pragma unroll
    for (int nt = 0; nt < 16; nt++) {
        int n = n0 + nt * 16 + l16;
        if (by == 0) {
            float bias = in_proj_b[n];
#pragma unroll
            for (int r = 0; r < 4; r++) {
                int m = m0 + quad * 4 + r;
                Qs[(size_t)m * E_ + n] = (bf16)((acc[nt][r] + bias) * QSCALE);
            }
        } else if (by == 1) {
            float bias = in_proj_b[n];
            int col = n - 256;
#pragma unroll
            for (int r = 0; r < 4; r++) {
                int m = m0 + quad * 4 + r;
                Ks[(size_t)m * E_ + col] = (bf16)(acc[nt][r] + bias);
            }
        } else {
            int nc = n - 512;
            float bias = B_gnn[nc];
            int m = m0 + quad * 4;
            int b = m >> 11, l = m & 2047;
            bf16x4 pk;
#pragma unroll
            for (int r = 0; r < 4; r++) pk[r] = (bf16)(acc[nt][r] + bias);
            *(bf16x4*)&XWT[((size_t)b * E_ + nc) * L_ + l] = pk;
        }
    }
}

// ---------------------------------------------------------------------------
// Kernel 3: softmax stats (r13 version: 128-key dbuf tiles).
// ---------------------------------------------------------------------------
__global__ __launch_bounds__(256, 4) void stats_kernel(
    const bf16* __restrict__ Qs, const bf16* __restrict__ Ks,
    float* __restrict__ o) {
    __shared__ bf16 ldsK[2][128 * 72];
    int tid  = threadIdx.x;
    int lane = tid & 63, wave = tid >> 6;
    int r32  = lane & 31, half = lane >> 5;
    int qt = blockIdx.x, h = blockIdx.y, b = blockIdx.z;
    int q0 = qt * 128 + wave * 32;

    bf16x8 qa[4];
    const bf16* qrow = Qs + ((size_t)b * L_ + q0 + r32) * E_ + h * D_;
#pragma unroll
    for (int c = 0; c < 4; c++) qa[c] = *(const bf16x8*)&qrow[c * 16 + half * 8];

    float lsum[16];
#pragma unroll
    for (int i = 0; i < 16; i++) lsum[i] = 0.f;

    const bf16* Kb = Ks + (size_t)b * L_ * E_ + h * D_;

#pragma unroll
    for (int it = 0; it < 4; it++) {
        int idx = it * 256 + tid;
        int key = idx >> 3, dc = (idx & 7) * 8;
        *(bf16x8*)&ldsK[0][key * 72 + dc] =
            *(const bf16x8*)&Kb[(size_t)key * E_ + dc];
    }
    __syncthreads();

    int cur = 0;
    for (int kt = 0; kt < 16; kt++) {
        bf16x8 pk[4];
        if (kt < 15) {
#pragma unroll
            for (int it = 0; it < 4; it++) {
                int idx = it * 256 + tid;
                pk[it] = *(const bf16x8*)&Kb[(size_t)((kt + 1) * 128 + (idx >> 3)) * E_ + (idx & 7) * 8];
            }
        }
#pragma unroll
        for (int nt = 0; nt < 4; nt++) {
            f32x16 S = {};
#pragma unroll
            for (int c = 0; c < 4; c++) {
                bf16x8 kb = *(const bf16x8*)&ldsK[cur][(nt * 32 + r32) * 72 + c * 16 + half * 8];
                S = __builtin_amdgcn_mfma_f32_32x32x16_bf16(qa[c], kb, S, 0, 0, 0);
            }
#pragma unroll
            for (int i = 0; i < 16; i++) lsum[i] += fexp2(S[i]);
        }
        if (kt < 15) {
#pragma unroll
            for (int it = 0; it < 4; it++) {
                int idx = it * 256 + tid;
                *(bf16x8*)&ldsK[cur ^ 1][(idx >> 3) * 72 + (idx & 7) * 8] = pk[it];
            }
        }
        barrier_lds();
        cur ^= 1;
    }
#pragma unroll
    for (int i = 0; i < 16; i++) {
        float v = lsum[i];
        v += __shfl_xor(v, 1); v += __shfl_xor(v, 2); v += __shfl_xor(v, 4);
        v += __shfl_xor(v, 8); v += __shfl_xor(v, 16);
        lsum[i] = v;
    }
    if (r32 == 0) {
        float* op = o + ((size_t)(b * H_ + h)) * L_ + q0;
#pragma unroll
        for (int i = 0; i < 16; i++) {
            int row = (i & 3) + 8 * (i >> 2) + 4 * half;
            op[row] = -(2.0f + flog2(lsum[i]));
        }
    }
}

// ---------------------------------------------------------------------------
// Kernel 4: pass 2, PRODUCER-CONSUMER wave specialization (r14 schedule;
// compile fix: named LDS pointers + ternary slot select -- pointer ARRAYS
// into LDS don't compile on gfx950 (addrspacecast static-init error)).
// One 512-thr block/CU (grid 256 = 8b x 32qt); q-tile 64; 32 intervals of
// 64 keys; no ksp split -> direct f32 store, reduce deleted.
// Waves 0-3 = QK producers (qf 64 + P/s 32 regs, NO acc); waves 4-7 = PV
// consumers (acc 64 regs, NO qf) -- splits the register wall (r1/r10/r11).
// Slot schedule, ONE lgkm-only barrier per interval:
//   interval k: producers read K[k&1], write P[k&1] + XW[k&1];
//   consumers read P/XW[(k-1)&1], write K[(k+1)&1]. No same-slot RW in an
//   interval; every cross-interval dep crosses one barrier. Epilogue: PV_31.
// LDS 159,744 B -> 1 block/CU, 1 producer + 1 consumer per SIMD.
// amdgpu_waves_per_eu(2,2) pins occupancy so regalloc gets 256 VGPR (r10:
// compiler capped 128 despite LDS-forced occupancy -> spill).
// Spill tripwire: VGPR_Count==128 + WRITE >> 17 MB.
// ---------------------------------------------------------------------------
__global__ void __launch_bounds__(512) __attribute__((amdgpu_waves_per_eu(2, 2)))
pass2_kernel(
    const bf16* __restrict__ Qs, const bf16* __restrict__ Ks,
    const bf16* __restrict__ XWT, const float* __restrict__ o,
    float* __restrict__ out) {
    __shared__ alignas(16) unsigned char smem[159744];
    bf16* ldsK0  = (bf16*)smem;              // [64][264]
    bf16* ldsK1  = (bf16*)(smem + 33792);    // [64][264]
    bf16* ldsXW0 = (bf16*)(smem + 67584);    // [256][72]
    bf16* ldsXW1 = (bf16*)(smem + 104448);   // [256][72]
    bf16* ldsP0  = (bf16*)(smem + 141312);   // [64][72]
    bf16* ldsP1  = (bf16*)(smem + 150528);   // [64][72]

    int tid  = threadIdx.x;
    int lane = tid & 63, wave = tid >> 6;
    int l32  = lane & 31, half = lane >> 5;

    int flat = blockIdx.x;
    int b  = flat & 7;          // batch == XCD (L2 pin)
    int qt = flat >> 3;         // 0..31
    int q0 = qt * 64;

    const bf16* Kb = Ks + (size_t)b * L_ * E_;
    const bf16* Xb = XWT + (size_t)b * E_ * L_;

    // prologue: all 8 waves stage K_0 -> ldsK0
#pragma unroll
    for (int it = 0; it < 4; it++) {
        int idx = it * 512 + tid;
        int key = idx >> 5, col = (idx & 31) * 8;
        *(bf16x8*)&ldsK0[key * 264 + col] =
            *(const bf16x8*)&Kb[(size_t)key * E_ + col];
    }
    __syncthreads();

    if (wave < 4) {
        // ================= PRODUCER (QK + softmax + XW staging) ============
        int pqh = wave & 1, pkh = wave >> 1;
        int qw = q0 + pqh * 32 + l32;

        bf16x8 qf[4][4];
        const bf16* qrow = Qs + ((size_t)b * L_ + qw) * E_;
#pragma unroll
        for (int h = 0; h < H_; h++)
#pragma unroll
            for (int c = 0; c < 4; c++)
                qf[h][c] = *(const bf16x8*)&qrow[h * 64 + c * 16 + half * 8];

        float oh[4];
#pragma unroll
        for (int h = 0; h < H_; h++)
            oh[h] = o[((size_t)(b * H_ + h)) * L_ + qw];

        f32x16 zero = {};
        for (int kt = 0; kt < 32; kt++) {
            bf16* kcur = (kt & 1) ? ldsK1  : ldsK0;
            bf16* xcur = (kt & 1) ? ldsXW1 : ldsXW0;
            bf16* pcur = (kt & 1) ? ldsP1  : ldsP0;

            // issue XW_kt loads (written this interval, read by consumers at kt+1)
            bf16x8 pxf[8];
#pragma unroll
            for (int it = 0; it < 8; it++) {
                int idx = it * 256 + tid;
                int n = idx >> 3, kc8 = (idx & 7) * 8;
                pxf[it] = *(const bf16x8*)&Xb[(size_t)n * L_ + kt * 64 + kc8];
            }

            // QK_kt: S^T quadrant (32k x 32q) per head; P = sum_h exp2(S^T+o_h)
            f32x16 P = zero;
#pragma unroll
            for (int h = 0; h < H_; h++) {
                f32x16 s = zero;
#pragma unroll
                for (int c = 0; c < 4; c++) {
                    bf16x8 ka = *(const bf16x8*)&kcur[(pkh * 32 + l32) * 264 + h * 64 + c * 16 + half * 8];
                    s = __builtin_amdgcn_mfma_f32_32x32x16_bf16(ka, qf[h][c], s, 0, 0, 0);
                }
#pragma unroll
                for (int r = 0; r < 16; r++) P[r] += fexp2(s[r] + oh[h]);
            }

            // P_kt at TRUE key indices (regs 4g..4g+3 -> keys 8g+4*half+0..3)
#pragma unroll
            for (int g = 0; g < 4; g++) {
                bf16x4 pk;
#pragma unroll
                for (int j = 0; j < 4; j++) pk[j] = (bf16)P[4 * g + j];
                *(bf16x4*)&pcur[(pqh * 32 + l32) * 72 + pkh * 32 + g * 8 + half * 4] = pk;
            }

            // XW_kt -> xcur (vmcnt wait here, covered by QK above)
#pragma unroll
            for (int it = 0; it < 8; it++) {
                int idx = it * 256 + tid;
                int n = idx >> 3, kc8 = (idx & 7) * 8;
                *(bf16x8*)&xcur[n * 72 + kc8] = pxf[it];
            }
            barrier_lds();
        }
        // producers done (no LDS use after final barrier)
    } else {
        // ================= CONSUMER (PV lag-1 + K staging) =================
        int cw = wave - 4;
        int cqh = cw & 1, cnh = cw >> 1;
        int ctid = tid - 256;   // 0..255

        f32x16 zero = {};
        f32x16 acc[4];
#pragma unroll
        for (int i = 0; i < 4; i++) acc[i] = zero;

        for (int kt = 0; kt < 32; kt++) {
            bf16* knext = (kt & 1) ? ldsK0  : ldsK1;   // slot (kt+1)&1
            bf16* xprev = (kt & 1) ? ldsXW0 : ldsXW1;  // slot (kt-1)&1
            bf16* pprev = (kt & 1) ? ldsP0  : ldsP1;   // slot (kt-1)&1

            // issue K_{kt+1} loads (written this interval into knext)
            bf16x8 pkf[8];
            if (kt < 31) {
#pragma unroll
                for (int it = 0; it < 8; it++) {
                    int idx = it * 256 + ctid;
                    int key = idx >> 5, col = (idx & 31) * 8;
                    pkf[it] = *(const bf16x8*)&Kb[(size_t)((kt + 1) * 64 + key) * E_ + col];
                }
            }

            // PV_{kt-1}: O[32q x 128n] += P[32q x 64k] @ XW[64k x 128n]
            if (kt > 0) {
#pragma unroll
                for (int kc = 0; kc < 4; kc++) {
                    bf16x8 pa = *(const bf16x8*)&pprev[(cqh * 32 + l32) * 72 + kc * 16 + half * 8];
#pragma unroll
                    for (int nt = 0; nt < 4; nt++) {
                        bf16x8 xw = *(const bf16x8*)&xprev[(cnh * 128 + nt * 32 + l32) * 72 + kc * 16 + half * 8];
                        acc[nt] = __builtin_amdgcn_mfma_f32_32x32x16_bf16(pa, xw, acc[nt], 0, 0, 0);
                    }
                }
            }

            // K_{kt+1} -> knext (vmcnt wait here, covered by PV above)
            if (kt < 31) {
#pragma unroll
                for (int it = 0; it < 8; it++) {
                    int idx = it * 256 + ctid;
                    int key = idx >> 5, col = (idx & 31) * 8;
                    *(bf16x8*)&knext[key * 264 + col] = pkf[it];
                }
            }
            barrier_lds();
        }

        // epilogue: PV_31 (P_31/XW_31 in slot 1, drained at final barrier)
#pragma unroll
        for (int kc = 0; kc < 4; kc++) {
            bf16x8 pa = *(const bf16x8*)&ldsP1[(cqh * 32 + l32) * 72 + kc * 16 + half * 8];
#pragma unroll
            for (int nt = 0; nt < 4; nt++) {
                bf16x8 xw = *(const bf16x8*)&ldsXW1[(cnh * 128 + nt * 32 + l32) * 72 + kc * 16 + half * 8];
                acc[nt] = __builtin_amdgcn_mfma_f32_32x32x16_bf16(pa, xw, acc[nt], 0, 0, 0);
            }
        }

        // direct store: consumer owns disjoint 32q x 128n of out[B,L,E]
        float* Ob = out + ((size_t)b * L_ + q0 + cqh * 32) * E_ + cnh * 128;
#pragma unroll
        for (int nt = 0; nt < 4; nt++)
#pragma unroll
            for (int r = 0; r < 16; r++) {
                int row = (r & 3) + 8 * (r >> 2) + 4 * half;
                Ob[(size_t)row * E_ + nt * 32 + l32] = acc[nt][r];
            }
    }
}

// ---------------------------------------------------------------------------
extern "C" void kernel_launch(void* const* d_in, const int* in_sizes, int n_in,
                              void* d_out, int out_size, void* d_ws, size_t ws_size,
                              hipStream_t stream) {
    const float* x   = (const float*)d_in[0];
    const float* ipw = (const float*)d_in[1];
    const float* ipb = (const float*)d_in[2];
    const float* wg  = (const float*)d_in[3];
    const float* bg  = (const float*)d_in[4];

    char* ws = (char*)d_ws;
    bf16*  Qs   = (bf16*)(ws);
    bf16*  Ks   = (bf16*)(ws + 8388608);
    bf16*  XWT  = (bf16*)(ws + 16777216);
    float* o    = (float*)(ws + 25165824);
    bf16*  xb   = (bf16*)(ws + 25427968);
    bf16*  Wcat = (bf16*)(ws + 33816576);

    prep_kernel<<<4864, 256, 0, stream>>>(x, ipw, wg, xb, Wcat);
    proj_kernel<<<dim3(256, 3), 256, 0, stream>>>(xb, Wcat, ipb, bg, Qs, Ks, XWT);
    stats_kernel<<<dim3(16, 4, 8), 256, 0, stream>>>(Qs, Ks, o);
    pass2_kernel<<<256, 512, 0, stream>>>(Qs, Ks, XWT, o, (float*)d_out);
}